// Round 1
// baseline (196.166 us; speedup 1.0000x reference)
//
#include <hip/hip_runtime.h>
#include <hip/hip_bf16.h>
#include <math.h>

#define NV 64
#define ND 64
#define NTOK 8192
#define LN_EPS 1e-5f
#define SROW 4096
#define WROW 4096
#define KSPLIT 8
#define KR2 (4096 / KSPLIT)     // 512
#define BK 64
#define NKC (KR2 / BK)          // 8
#define PROW2 (KSPLIT * 128)    // 1024

typedef __attribute__((ext_vector_type(8))) short s8v;    // 8 bf16 = 4 VGPR
typedef __attribute__((ext_vector_type(4))) float f4v;    // MFMA C/D
typedef __attribute__((ext_vector_type(4))) int   i4v;

__device__ __forceinline__ float sigm_f(float x) {
    return __builtin_amdgcn_rcpf(1.f + __expf(-x));
}
__device__ __forceinline__ float elu_f(float x)  { return x > 0.f ? x : (__expf(x) - 1.f); }

__device__ __forceinline__ float bf16_to_f(unsigned short s) {
    union { unsigned int u; float f; } c; c.u = ((unsigned int)s) << 16;
    return c.f;
}
__device__ __forceinline__ unsigned short bf16_rn(float f) {
    union { float f; unsigned int u; } c; c.f = f;
    return (unsigned short)((c.u + 0x8000u) >> 16);
}
// round-to-nearest pack of 2 floats -> 2 bf16 in a dword
__device__ __forceinline__ unsigned int pk2rn(float a, float b) {
    return (unsigned int)bf16_rn(a) | ((unsigned int)bf16_rn(b) << 16);
}
// truncating pack (matches previous kernel's h1/h2 handling)
__device__ __forceinline__ unsigned int pk2t(float a, float b) {
    return (__float_as_uint(a) >> 16) | (__float_as_uint(b) & 0xffff0000u);
}
// async global->LDS 16B (lds ptr must be wave-uniform; lane writes base + lane*16)
__device__ __forceinline__ void async16(const void* g, void* l) {
    __builtin_amdgcn_global_load_lds(
        (const __attribute__((address_space(1))) unsigned int*)g,
        (__attribute__((address_space(3))) unsigned int*)l,
        16, 0, 0);
}

// ---------------- Prepack: weight transposes via LDS tiles (coalesced R+W)
// UNCHANGED: w2b[e][k]=W2[k][e], wgb[e][k]=Wg[k][e], wct[n][k] = [Wn1|Wns]^T
__global__ __launch_bounds__(256) void vsn_prepack(
    const float* __restrict__ W2, const float* __restrict__ Wg,
    const float* __restrict__ Wn1, const float* __restrict__ Wns,
    short* __restrict__ w2b, short* __restrict__ wgb,
    short* __restrict__ wct)
{
    __shared__ float T[64][65];
    const int b = blockIdx.x, t = threadIdx.x;

    if (b < 64) {
        const float* src = W2 + (size_t)b * 4096;
        short* dst = w2b + (size_t)b * 4096;
        #pragma unroll
        for (int pass = 0; pass < 2; ++pass) {
            #pragma unroll
            for (int i = 0; i < 16; ++i) {
                int id = i * 256 + t;
                T[id & 63][id >> 6] = src[id];
            }
            __syncthreads();
            #pragma unroll
            for (int i = 0; i < 16; ++i) {
                int id = i * 256 + t;
                dst[id] = (short)bf16_rn(T[id >> 6][id & 63]);
            }
            __syncthreads();
            src = Wg + (size_t)b * 4096;
            dst = wgb + (size_t)b * 4096;
        }
    } else {
        int tb = b - 64;
        int half = tb >> 6, kt = tb & 63;
        const float* src = (half == 0 ? Wn1 : Wns) + (size_t)(kt * 64) * 64;
        #pragma unroll
        for (int i = 0; i < 16; ++i) {
            int id = i * 256 + t;
            T[id & 63][id >> 6] = src[id];
        }
        __syncthreads();
        #pragma unroll
        for (int i = 0; i < 16; ++i) {
            int id = i * 256 + t;
            int n = id >> 6, r = id & 63;
            wct[(size_t)(half * 64 + n) * WROW + kt * 64 + r] = (short)bf16_rn(T[n][r]);
        }
    }
}

// ---------------- Stage 1 (SWAPPED layout): compute W2^T@h1^T / Wg^T@h2^T so
// tokens land on the m16 lane axis and d on the register axis.
// Per lane: 16 consecutive-d values (ei*16+quad*4+r) of 2 tokens (ti*16+m16).
// -> ds_writes 32xb16 -> 8xb64; LN shuffles 64 -> 8; stores 32xb16 -> 8xb64.
__global__ __launch_bounds__(256) void vsn_stage1(
    const float* __restrict__ x,
    const float* __restrict__ W1, const float* __restrict__ b1,
    const short* __restrict__ w2b, const short* __restrict__ wgb,
    const float* __restrict__ b2, const float* __restrict__ bg,
    const float* __restrict__ Wsk, const float* __restrict__ bsk,
    const float* __restrict__ gamma, const float* __restrict__ beta,
    unsigned short* __restrict__ stb)
{
    const int t = threadIdx.x;
    const int wave = t >> 6, lane = t & 63;
    const int m16 = lane & 15, quad = lane >> 4;
    const int v = blockIdx.y * 4 + wave;

    __shared__ __align__(16) unsigned short h2s[4][32][72];  // [wave][tok][e] pad72
    __shared__ __align__(16) float pl[4][6][64];             // b2,bg,Wsk,bsk,gam,bet

    // per-wave param staging (same-wave writes+reads; no barrier needed)
    {
        int dd = lane;
        pl[wave][0][dd] = b2[v * 64 + dd];
        pl[wave][1][dd] = bg[v * 64 + dd];
        pl[wave][2][dd] = Wsk[v * 64 + dd];
        pl[wave][3][dd] = bsk[v * 64 + dd];
        pl[wave][4][dd] = gamma[v * 64 + dd];
        pl[wave][5][dd] = beta[v * 64 + dd];
    }

    float w1k[2][8], b1k[2][8];
    #pragma unroll
    for (int kt = 0; kt < 2; ++kt) {
        *(float4*)&w1k[kt][0] = *(const float4*)(W1 + v * 64 + kt * 32 + quad * 8);
        *(float4*)&w1k[kt][4] = *(const float4*)(W1 + v * 64 + kt * 32 + quad * 8 + 4);
        *(float4*)&b1k[kt][0] = *(const float4*)(b1 + v * 64 + kt * 32 + quad * 8);
        *(float4*)&b1k[kt][4] = *(const float4*)(b1 + v * 64 + kt * 32 + quad * 8 + 4);
    }
    const size_t wb = (size_t)v * 4096;

    for (int tt4 = 0; tt4 < 4; ++tt4) {
        const int tile0 = blockIdx.x * 128 + tt4 * 32;

        // x broadcast via shfl (no LDS round trip)
        float xld = x[(size_t)(tile0 + (lane & 31)) * NV + v];
        float xv[2];
        xv[0] = __shfl(xld, m16);
        xv[1] = __shfl(xld, 16 + m16);

        // h1^T B-fragments: lane m16 = token, regs = k
        s8v bh1[2][2];
        #pragma unroll
        for (int ti = 0; ti < 2; ++ti)
            #pragma unroll
            for (int kt = 0; kt < 2; ++kt) {
                float h[8];
                #pragma unroll
                for (int j = 0; j < 8; ++j) h[j] = elu_f(fmaf(xv[ti], w1k[kt][j], b1k[kt][j]));
                i4v av;
                #pragma unroll
                for (int p = 0; p < 4; ++p)
                    av[p] = (int)pk2t(h[2 * p], h[2 * p + 1]);
                bh1[ti][kt] = *(s8v*)&av;
            }

        // GEMM1: hacc[ei][ti] = W2^T @ h1^T  (rows=e on quad*4+r, cols=tok on m16)
        f4v hacc[4][2];
        #pragma unroll
        for (int ei = 0; ei < 4; ++ei)
            #pragma unroll
            for (int ti = 0; ti < 2; ++ti) hacc[ei][ti] = (f4v){0.f, 0.f, 0.f, 0.f};
        #pragma unroll
        for (int kt = 0; kt < 2; ++kt)
            #pragma unroll
            for (int ei = 0; ei < 4; ++ei) {
                s8v aw = *(const s8v*)(w2b + wb + (size_t)(ei * 16 + m16) * 64 + kt * 32 + quad * 8);
                #pragma unroll
                for (int ti = 0; ti < 2; ++ti)
                    hacc[ei][ti] = __builtin_amdgcn_mfma_f32_16x16x32_bf16(aw, bh1[ti][kt], hacc[ei][ti], 0, 0, 0);
            }

        // + b2 (broadcast float4 from LDS), then h2 -> LDS as [tok][e] b64 writes
        #pragma unroll
        for (int ei = 0; ei < 4; ++ei) {
            float bq[4];
            *(float4*)bq = *(const float4*)&pl[wave][0][ei * 16 + quad * 4];
            #pragma unroll
            for (int ti = 0; ti < 2; ++ti) {
                #pragma unroll
                for (int r = 0; r < 4; ++r) hacc[ei][ti][r] += bq[r];
                uint2 pk = make_uint2(pk2t(hacc[ei][ti][0], hacc[ei][ti][1]),
                                      pk2t(hacc[ei][ti][2], hacc[ei][ti][3]));
                *(uint2*)&h2s[wave][ti * 16 + m16][ei * 16 + quad * 4] = pk;
            }
        }

        // GEMM2: gacc[ei][ti] = Wg^T @ h2^T ; h2 B-frags from LDS (b128)
        s8v bh2[2][2];
        #pragma unroll
        for (int ti = 0; ti < 2; ++ti)
            #pragma unroll
            for (int kt = 0; kt < 2; ++kt)
                bh2[ti][kt] = *(const s8v*)&h2s[wave][ti * 16 + m16][kt * 32 + quad * 8];

        f4v gacc[4][2];
        #pragma unroll
        for (int ei = 0; ei < 4; ++ei)
            #pragma unroll
            for (int ti = 0; ti < 2; ++ti) gacc[ei][ti] = (f4v){0.f, 0.f, 0.f, 0.f};
        #pragma unroll
        for (int kt = 0; kt < 2; ++kt)
            #pragma unroll
            for (int ei = 0; ei < 4; ++ei) {
                s8v ag = *(const s8v*)(wgb + wb + (size_t)(ei * 16 + m16) * 64 + kt * 32 + quad * 8);
                #pragma unroll
                for (int ti = 0; ti < 2; ++ti)
                    gacc[ei][ti] = __builtin_amdgcn_mfma_f32_16x16x32_bf16(ag, bh2[ti][kt], gacc[ei][ti], 0, 0, 0);
            }

        // gate + skip combine (all in-register)
        #pragma unroll
        for (int ei = 0; ei < 4; ++ei) {
            float bgq[4], wkq[4], bkq[4];
            *(float4*)bgq = *(const float4*)&pl[wave][1][ei * 16 + quad * 4];
            *(float4*)wkq = *(const float4*)&pl[wave][2][ei * 16 + quad * 4];
            *(float4*)bkq = *(const float4*)&pl[wave][3][ei * 16 + quad * 4];
            #pragma unroll
            for (int ti = 0; ti < 2; ++ti)
                #pragma unroll
                for (int r = 0; r < 4; ++r) {
                    float g = sigm_f(gacc[ei][ti][r] + bgq[r]);
                    gacc[ei][ti][r] = fmaf(xv[ti], wkq[r], bkq[r]) + g * hacc[ei][ti][r];
                }
        }

        // LN over d: 16 in-lane partials + 2 quad-axis shuffles per value
        float mu[2], rs[2];
        #pragma unroll
        for (int ti = 0; ti < 2; ++ti) {
            float sum = 0.f, sq = 0.f;
            #pragma unroll
            for (int ei = 0; ei < 4; ++ei)
                #pragma unroll
                for (int r = 0; r < 4; ++r) {
                    float z = gacc[ei][ti][r];
                    sum += z; sq = fmaf(z, z, sq);
                }
            sum += __shfl_xor(sum, 16); sq += __shfl_xor(sq, 16);
            sum += __shfl_xor(sum, 32); sq += __shfl_xor(sq, 32);
            mu[ti] = sum * 0.015625f;
            float var = sq * 0.015625f - mu[ti] * mu[ti];
            rs[ti] = __builtin_amdgcn_rsqf(var + LN_EPS);
        }

        // normalize + pack + b64 stores (16 tokens x 32B contiguous per inst)
        #pragma unroll
        for (int ei = 0; ei < 4; ++ei) {
            float gq[4], bq[4];
            *(float4*)gq = *(const float4*)&pl[wave][4][ei * 16 + quad * 4];
            *(float4*)bq = *(const float4*)&pl[wave][5][ei * 16 + quad * 4];
            #pragma unroll
            for (int ti = 0; ti < 2; ++ti) {
                float n0 = (gacc[ei][ti][0] - mu[ti]) * rs[ti] * gq[0] + bq[0];
                float n1 = (gacc[ei][ti][1] - mu[ti]) * rs[ti] * gq[1] + bq[1];
                float n2 = (gacc[ei][ti][2] - mu[ti]) * rs[ti] * gq[2] + bq[2];
                float n3 = (gacc[ei][ti][3] - mu[ti]) * rs[ti] * gq[3] + bq[3];
                uint2 pk = make_uint2(pk2rn(n0, n1), pk2rn(n2, n3));
                *(uint2*)(stb + (size_t)(tile0 + ti * 16 + m16) * SROW
                          + v * 64 + ei * 16 + quad * 4) = pk;
            }
        }
    }
}

// ---------------- Stage 2a: LDS GEMM via global_load_lds (width 16) + T2 XOR
// swizzle (linear LDS dest, inverse-swizzled source, swizzled ds_read).
// Double-buffered, 1 barrier per K-step. tile M=128 x N=128, BK=64, 8 waves.
__global__ __launch_bounds__(512) void vsn_stage2a(
    const unsigned short* __restrict__ stb,   // [8192][SROW]
    const short* __restrict__ wct,            // [128][WROW]
    float* __restrict__ part)                 // [8192][PROW2]
{
    const int t = threadIdx.x;
    const int wave = t >> 6, lane = t & 63;
    const int m16 = lane & 15, quad = lane >> 4;
    const int mw = wave & 3, nw = wave >> 2;
    const int tok0 = blockIdx.x * 128;
    const int s = blockIdx.y;
    const int k0 = s * KR2;

    // linear [row][64] shorts, 2 buffers each for A and B (64 KiB total)
    __shared__ __align__(16) unsigned short Al[2][128 * 64];
    __shared__ __align__(16) unsigned short Bl[2][128 * 64];

    const int srow = t >> 3;            // 0..63 (+64 for q=1)
    const int schunk = t & 7;           // 16B chunk within the 128B row

    f4v acc[2][4];
    #pragma unroll
    for (int mi = 0; mi < 2; ++mi)
        #pragma unroll
        for (int nj = 0; nj < 4; ++nj) acc[mi][nj] = (f4v){0.f, 0.f, 0.f, 0.f};

    auto STAGE = [&](int buf, int kc) {
        const int kb = k0 + kc * BK;
        #pragma unroll
        for (int q = 0; q < 2; ++q) {
            const int row = srow + q * 64;
            const int sc = (schunk ^ (row & 7)) * 8;   // inverse-swizzled source col (shorts)
            // wave-uniform LDS base: bytes q*8192 + wave*1024 -> shorts q*4096 + wave*512
            async16(stb + (size_t)(tok0 + row) * SROW + kb + sc,
                    &Al[buf][q * 4096 + wave * 512]);
            async16(wct + (size_t)row * WROW + kb + sc,
                    &Bl[buf][q * 4096 + wave * 512]);
        }
    };

    STAGE(0, 0);
    __syncthreads();                    // drains vmcnt(0): buf0 ready

    for (int kc = 0; kc < NKC; ++kc) {
        const int buf = kc & 1;
        if (kc + 1 < NKC) STAGE(buf ^ 1, kc + 1);   // async into other buffer
        #pragma unroll
        for (int ks = 0; ks < 2; ++ks) {
            s8v af[2], bfr[4];
            #pragma unroll
            for (int mi = 0; mi < 2; ++mi) {
                int row = mw * 32 + mi * 16 + m16;
                int ch = ((ks * 4 + quad) ^ (row & 7)) * 8;     // swizzled read
                af[mi] = *(const s8v*)&Al[buf][row * 64 + ch];
            }
            #pragma unroll
            for (int nj = 0; nj < 4; ++nj) {
                int row = nw * 64 + nj * 16 + m16;
                int ch = ((ks * 4 + quad) ^ (row & 7)) * 8;
                bfr[nj] = *(const s8v*)&Bl[buf][row * 64 + ch];
            }
            #pragma unroll
            for (int mi = 0; mi < 2; ++mi)
                #pragma unroll
                for (int nj = 0; nj < 4; ++nj)
                    acc[mi][nj] = __builtin_amdgcn_mfma_f32_16x16x32_bf16(af[mi], bfr[nj], acc[mi][nj], 0, 0, 0);
        }
        __syncthreads();                // drains vmcnt (next buf ready) + guards reuse
    }

    #pragma unroll
    for (int mi = 0; mi < 2; ++mi)
        #pragma unroll
        for (int nj = 0; nj < 4; ++nj)
            #pragma unroll
            for (int r = 0; r < 4; ++r)
                part[(size_t)(tok0 + mw * 32 + mi * 16 + quad * 4 + r) * PROW2
                     + s * 128 + nw * 64 + nj * 16 + m16] = acc[mi][nj][r];
}

// ---------------- Stage 2b: reduce 8 contiguous partials, tail GRN, softmax, weighted sum
// UNCHANGED this round.
__global__ __launch_bounds__(256) void vsn_stage2b(
    const unsigned short* __restrict__ stb, const float* __restrict__ part,
    const float* __restrict__ bn1,
    const float* __restrict__ Wn2, const float* __restrict__ bn2,
    const float* __restrict__ Wng, const float* __restrict__ bng,
    const float* __restrict__ bns,
    const float* __restrict__ ngamma, const float* __restrict__ nbeta,
    float* __restrict__ out)
{
    const int t = threadIdx.x;
    const int tok0 = blockIdx.x * 8;
    const int lane = t & 63, wv = t >> 6;

    __shared__ __align__(16) float hw1_s[8][64];
    __shared__ __align__(16) float skw_s[8][64];
    __shared__ __align__(16) float hw2_s[8][64];
    __shared__ float s2_s[8][64];
    __shared__ float w_s[8][64];

    #pragma unroll
    for (int tk = 0; tk < 2; ++tk) {
        int tl = wv * 2 + tk;
        const float* pr = part + (size_t)(tok0 + tl) * PROW2
                        + (lane >> 5) * 128 + (lane & 31) * 4;
        float tv[4] = {0.f, 0.f, 0.f, 0.f};
        #pragma unroll
        for (int i = 0; i < 4; ++i) {
            float4 a = *(const float4*)(pr + i * 256);
            tv[0] += a.x; tv[1] += a.y; tv[2] += a.z; tv[3] += a.w;
        }
        #pragma unroll
        for (int c = 0; c < 4; ++c) tv[c] += __shfl_xor(tv[c], 32);
        if (lane < 16) {
            int j0 = lane * 4;
            float4 bb = *(const float4*)(bn1 + j0);
            hw1_s[tl][j0 + 0] = elu_f(tv[0] + bb.x);
            hw1_s[tl][j0 + 1] = elu_f(tv[1] + bb.y);
            hw1_s[tl][j0 + 2] = elu_f(tv[2] + bb.z);
            hw1_s[tl][j0 + 3] = elu_f(tv[3] + bb.w);
        } else if (lane < 32) {
            int j0 = (lane - 16) * 4;
            float4 bb = *(const float4*)(bns + j0);
            skw_s[tl][j0 + 0] = tv[0] + bb.x;
            skw_s[tl][j0 + 1] = tv[1] + bb.y;
            skw_s[tl][j0 + 2] = tv[2] + bb.z;
            skw_s[tl][j0 + 3] = tv[3] + bb.w;
        }
    }
    __syncthreads();

    #pragma unroll
    for (int i = 0; i < 2; ++i) {
        int oidx = i * 256 + t;
        int tt = oidx >> 6, jj = oidx & 63;
        float acc = bn2[jj];
        #pragma unroll
        for (int k4 = 0; k4 < 16; ++k4) {
            float4 h = *(const float4*)&hw1_s[tt][k4 * 4];
            acc += h.x * Wn2[(k4*4+0)*64+jj] + h.y * Wn2[(k4*4+1)*64+jj]
                 + h.z * Wn2[(k4*4+2)*64+jj] + h.w * Wn2[(k4*4+3)*64+jj];
        }
        hw2_s[tt][jj] = acc;
    }
    __syncthreads();

    #pragma unroll
    for (int i = 0; i < 2; ++i) {
        int oidx = i * 256 + t;
        int tt = oidx >> 6, vv = oidx & 63;
        float acc = bng[vv];
        #pragma unroll
        for (int k4 = 0; k4 < 16; ++k4) {
            float4 h = *(const float4*)&hw2_s[tt][k4 * 4];
            acc += h.x * Wng[(k4*4+0)*64+vv] + h.y * Wng[(k4*4+1)*64+vv]
                 + h.z * Wng[(k4*4+2)*64+vv] + h.w * Wng[(k4*4+3)*64+vv];
        }
        float gw = sigm_f(acc);
        s2_s[tt][vv] = skw_s[tt][vv] + gw * hw2_s[tt][vv];
    }
    __syncthreads();

    const int vloc = lane >> 3, d8 = (lane & 7) * 8;
    s8v r0[8], r1[8];
    {
        const short* s0 = (const short*)stb + (size_t)(tok0 + wv * 2) * SROW + d8;
        const short* s1 = s0 + SROW;
        #pragma unroll
        for (int vc = 0; vc < 8; ++vc) {
            r0[vc] = *(const s8v*)(s0 + (vc * 8 + vloc) * 64);
            r1[vc] = *(const s8v*)(s1 + (vc * 8 + vloc) * 64);
        }
    }

    if (t < 128) {
        int tt = t >> 4, l = t & 15;
        float z[4]; float sum = 0.f, sq = 0.f;
        #pragma unroll
        for (int i = 0; i < 4; ++i) { z[i] = s2_s[tt][l + 16 * i]; sum += z[i]; sq += z[i] * z[i]; }
        #pragma unroll
        for (int m = 1; m < 16; m <<= 1) { sum += __shfl_xor(sum, m); sq += __shfl_xor(sq, m); }
        float mu  = sum * 0.015625f;
        float var = sq * 0.015625f - mu * mu;
        float rs  = __builtin_amdgcn_rsqf(var + LN_EPS);
        float ln[4]; float mx = -1e30f;
        #pragma unroll
        for (int i = 0; i < 4; ++i) {
            ln[i] = (z[i] - mu) * rs * ngamma[l + 16 * i] + nbeta[l + 16 * i];
            mx = fmaxf(mx, ln[i]);
        }
        #pragma unroll
        for (int m = 1; m < 16; m <<= 1) mx = fmaxf(mx, __shfl_xor(mx, m));
        float es = 0.f; float ev[4];
        #pragma unroll
        for (int i = 0; i < 4; ++i) { ev[i] = __expf(ln[i] - mx); es += ev[i]; }
        #pragma unroll
        for (int m = 1; m < 16; m <<= 1) es += __shfl_xor(es, m);
        float inv = __builtin_amdgcn_rcpf(es);
        #pragma unroll
        for (int i = 0; i < 4; ++i) w_s[tt][l + 16 * i] = ev[i] * inv;
    }
    __syncthreads();

    {
        float acc0[8], acc1[8];
        #pragma unroll
        for (int j = 0; j < 8; ++j) { acc0[j] = 0.f; acc1[j] = 0.f; }
        #pragma unroll
        for (int vc = 0; vc < 8; ++vc) {
            int v = vc * 8 + vloc;
            float w0 = w_s[wv * 2][v], w1 = w_s[wv * 2 + 1][v];
            #pragma unroll
            for (int j = 0; j < 8; ++j) {
                acc0[j] = fmaf(w0, bf16_to_f((unsigned short)r0[vc][j]), acc0[j]);
                acc1[j] = fmaf(w1, bf16_to_f((unsigned short)r1[vc][j]), acc1[j]);
            }
        }
        #pragma unroll
        for (int m = 8; m <= 32; m <<= 1)
            #pragma unroll
            for (int j = 0; j < 8; ++j) {
                acc0[j] += __shfl_xor(acc0[j], m);
                acc1[j] += __shfl_xor(acc1[j], m);
            }
        if (lane < 8) {
            float* op = out + (size_t)(tok0 + wv * 2) * 64 + lane * 8;
            *(float4*)op       = make_float4(acc0[0], acc0[1], acc0[2], acc0[3]);
            *(float4*)(op + 4) = make_float4(acc0[4], acc0[5], acc0[6], acc0[7]);
            op += 64;
            *(float4*)op       = make_float4(acc1[0], acc1[1], acc1[2], acc1[3]);
            *(float4*)(op + 4) = make_float4(acc1[4], acc1[5], acc1[6], acc1[7]);
        }
    }
}

extern "C" void kernel_launch(void* const* d_in, const int* in_sizes, int n_in,
                              void* d_out, int out_size, void* d_ws, size_t ws_size,
                              hipStream_t stream) {
    const float* x     = (const float*)d_in[0];
    const float* W1    = (const float*)d_in[1];
    const float* b1    = (const float*)d_in[2];
    const float* W2    = (const float*)d_in[3];
    const float* b2    = (const float*)d_in[4];
    const float* Wg    = (const float*)d_in[5];
    const float* bg    = (const float*)d_in[6];
    const float* Wsk   = (const float*)d_in[7];
    const float* bsk   = (const float*)d_in[8];
    const float* gamma = (const float*)d_in[9];
    const float* beta  = (const float*)d_in[10];
    const float* Wn1   = (const float*)d_in[11];
    const float* bn1   = (const float*)d_in[12];
    const float* Wn2   = (const float*)d_in[13];
    const float* bn2   = (const float*)d_in[14];
    const float* Wng   = (const float*)d_in[15];
    const float* bng   = (const float*)d_in[16];
    const float* Wns   = (const float*)d_in[17];
    const float* bns   = (const float*)d_in[18];
    const float* ngam  = (const float*)d_in[19];
    const float* nbet  = (const float*)d_in[20];

    char* ws = (char*)d_ws;
    unsigned short* stb = (unsigned short*)ws;                   // 64 MiB
    short* wct = (short*)(ws + (64u << 20));                     // 1 MiB
    short* w2b = (short*)(ws + (65u << 20));                     // 512 KiB each
    short* wgb = w2b + 262144;
    float* part = (float*)(ws + (66u << 20));                    // 32 MiB (8192 x 1024)
    float* outp = (float*)d_out;

    vsn_prepack<<<dim3(192), 256, 0, stream>>>(W2, Wg, Wn1, Wns, w2b, wgb, wct);
    vsn_stage1<<<dim3(NTOK / 128, 16), 256, 0, stream>>>(
        x, W1, b1, w2b, wgb, b2, bg, Wsk, bsk, gamma, beta, stb);
    vsn_stage2a<<<dim3(NTOK / 128, KSPLIT), 512, 0, stream>>>(stb, wct, part);
    vsn_stage2b<<<dim3(NTOK / 8), 256, 0, stream>>>(
        stb, part, bn1, Wn2, bn2, Wng, bng, bns, ngam, nbet, outp);
}

// Round 2
// 190.442 us; speedup vs baseline: 1.0301x; 1.0301x over previous
//
#include <hip/hip_runtime.h>
#include <hip/hip_bf16.h>
#include <math.h>

#define NV 64
#define ND 64
#define NTOK 8192
#define LN_EPS 1e-5f
#define SROW 4096
#define WROW 4096
#define KSPLIT 4
#define KR2 (4096 / KSPLIT)     // 1024
#define BK 64
#define NKC (KR2 / BK)          // 16
#define MT2 64                  // stage2a token tile
#define PROW2 (KSPLIT * 128)    // 512

typedef __attribute__((ext_vector_type(8))) short s8v;    // 8 bf16 = 4 VGPR
typedef __attribute__((ext_vector_type(4))) float f4v;    // MFMA C/D
typedef __attribute__((ext_vector_type(4))) int   i4v;

__device__ __forceinline__ float sigm_f(float x) {
    return __builtin_amdgcn_rcpf(1.f + __expf(-x));
}
__device__ __forceinline__ float elu_f(float x)  { return x > 0.f ? x : (__expf(x) - 1.f); }

__device__ __forceinline__ float bf16_to_f(unsigned short s) {
    union { unsigned int u; float f; } c; c.u = ((unsigned int)s) << 16;
    return c.f;
}
__device__ __forceinline__ unsigned short bf16_rn(float f) {
    union { float f; unsigned int u; } c; c.f = f;
    return (unsigned short)((c.u + 0x8000u) >> 16);
}
// async global->LDS 16B (lds base wave-uniform; lane l writes base + l*16B)
__device__ __forceinline__ void async16(const void* g, void* l) {
    __builtin_amdgcn_global_load_lds(
        (const __attribute__((address_space(1))) unsigned int*)g,
        (__attribute__((address_space(3))) unsigned int*)l,
        16, 0, 0);
}

// ---------------- Prepack: weight transposes via LDS tiles (coalesced R+W)
__global__ __launch_bounds__(256) void vsn_prepack(
    const float* __restrict__ W2, const float* __restrict__ Wg,
    const float* __restrict__ Wn1, const float* __restrict__ Wns,
    short* __restrict__ w2b, short* __restrict__ wgb,
    short* __restrict__ wct)
{
    __shared__ float T[64][65];
    const int b = blockIdx.x, t = threadIdx.x;

    if (b < 64) {
        const float* src = W2 + (size_t)b * 4096;
        short* dst = w2b + (size_t)b * 4096;
        #pragma unroll
        for (int pass = 0; pass < 2; ++pass) {
            #pragma unroll
            for (int i = 0; i < 16; ++i) {
                int id = i * 256 + t;
                T[id & 63][id >> 6] = src[id];
            }
            __syncthreads();
            #pragma unroll
            for (int i = 0; i < 16; ++i) {
                int id = i * 256 + t;
                dst[id] = (short)bf16_rn(T[id >> 6][id & 63]);
            }
            __syncthreads();
            src = Wg + (size_t)b * 4096;
            dst = wgb + (size_t)b * 4096;
        }
    } else {
        int tb = b - 64;
        int half = tb >> 6, kt = tb & 63;
        const float* src = (half == 0 ? Wn1 : Wns) + (size_t)(kt * 64) * 64;
        #pragma unroll
        for (int i = 0; i < 16; ++i) {
            int id = i * 256 + t;
            T[id & 63][id >> 6] = src[id];
        }
        __syncthreads();
        #pragma unroll
        for (int i = 0; i < 16; ++i) {
            int id = i * 256 + t;
            int n = id >> 6, r = id & 63;
            wct[(size_t)(half * 64 + n) * WROW + kt * 64 + r] = (short)bf16_rn(T[n][r]);
        }
    }
}

// ---------------- Stage 1: REVERTED to round-0 verified version (51.5us).
// d-on-lane layout: 24 param regs, VGPR=128 -> 4 waves/SIMD.
__global__ __launch_bounds__(256) void vsn_stage1(
    const float* __restrict__ x,
    const float* __restrict__ W1, const float* __restrict__ b1,
    const short* __restrict__ w2b, const short* __restrict__ wgb,
    const float* __restrict__ b2, const float* __restrict__ bg,
    const float* __restrict__ Wsk, const float* __restrict__ bsk,
    const float* __restrict__ gamma, const float* __restrict__ beta,
    unsigned short* __restrict__ stb)
{
    const int t = threadIdx.x;
    const int wave = t >> 6, lane = t & 63;
    const int m16 = lane & 15, quad = lane >> 4;
    const int v = blockIdx.y * 4 + wave;

    __shared__ float xs[4][32];
    __shared__ __align__(16) unsigned short h2s[4][32][72];

    float w1k[2][8], b1k[2][8];
    #pragma unroll
    for (int kt = 0; kt < 2; ++kt) {
        *(float4*)&w1k[kt][0] = *(const float4*)(W1 + v * 64 + kt * 32 + quad * 8);
        *(float4*)&w1k[kt][4] = *(const float4*)(W1 + v * 64 + kt * 32 + quad * 8 + 4);
        *(float4*)&b1k[kt][0] = *(const float4*)(b1 + v * 64 + kt * 32 + quad * 8);
        *(float4*)&b1k[kt][4] = *(const float4*)(b1 + v * 64 + kt * 32 + quad * 8 + 4);
    }
    float b2d[4], bgd[4], wskd[4], bskd[4], gamd[4], betd[4];
    #pragma unroll
    for (int ni = 0; ni < 4; ++ni) {
        int d = v * 64 + ni * 16 + m16;
        b2d[ni] = b2[d]; bgd[ni] = bg[d]; wskd[ni] = Wsk[d]; bskd[ni] = bsk[d];
        gamd[ni] = gamma[d]; betd[ni] = beta[d];
    }
    const size_t wb = (size_t)v * 4096;

    for (int tt4 = 0; tt4 < 4; ++tt4) {
        const int tile0 = blockIdx.x * 128 + tt4 * 32;

        if (lane < 32) xs[wave][lane] = x[(size_t)(tile0 + lane) * NV + v];

        s8v a[2][2];
        #pragma unroll
        for (int kt = 0; kt < 2; ++kt)
            #pragma unroll
            for (int mi = 0; mi < 2; ++mi) {
                float xv = xs[wave][mi * 16 + m16];
                float h[8];
                #pragma unroll
                for (int j = 0; j < 8; ++j) h[j] = elu_f(fmaf(xv, w1k[kt][j], b1k[kt][j]));
                i4v av;
                #pragma unroll
                for (int p = 0; p < 4; ++p) {
                    unsigned int u0 = __float_as_uint(h[2 * p]);
                    unsigned int u1 = __float_as_uint(h[2 * p + 1]);
                    av[p] = (int)((u1 & 0xffff0000u) | (u0 >> 16));
                }
                a[mi][kt] = *(s8v*)&av;
            }

        f4v hacc[2][4];
        #pragma unroll
        for (int mi = 0; mi < 2; ++mi)
            #pragma unroll
            for (int ni = 0; ni < 4; ++ni) hacc[mi][ni] = (f4v){0.f, 0.f, 0.f, 0.f};
        #pragma unroll
        for (int ni = 0; ni < 4; ++ni)
            #pragma unroll
            for (int kt = 0; kt < 2; ++kt) {
                s8v bh = *(const s8v*)(w2b + wb + (size_t)(ni * 16 + m16) * 64 + kt * 32 + quad * 8);
                #pragma unroll
                for (int mi = 0; mi < 2; ++mi)
                    hacc[mi][ni] = __builtin_amdgcn_mfma_f32_16x16x32_bf16(a[mi][kt], bh, hacc[mi][ni], 0, 0, 0);
            }
        #pragma unroll
        for (int mi = 0; mi < 2; ++mi)
            #pragma unroll
            for (int ni = 0; ni < 4; ++ni)
                #pragma unroll
                for (int r = 0; r < 4; ++r) hacc[mi][ni][r] += b2d[ni];

        #pragma unroll
        for (int mi = 0; mi < 2; ++mi)
            #pragma unroll
            for (int ni = 0; ni < 4; ++ni)
                #pragma unroll
                for (int r = 0; r < 4; ++r)
                    h2s[wave][mi * 16 + quad * 4 + r][ni * 16 + m16] =
                        (unsigned short)(__float_as_uint(hacc[mi][ni][r]) >> 16);

        s8v c[2][2];
        #pragma unroll
        for (int mi = 0; mi < 2; ++mi)
            #pragma unroll
            for (int kt = 0; kt < 2; ++kt)
                c[mi][kt] = *(const s8v*)&h2s[wave][mi * 16 + m16][kt * 32 + quad * 8];

        f4v gacc[2][4];
        #pragma unroll
        for (int mi = 0; mi < 2; ++mi)
            #pragma unroll
            for (int ni = 0; ni < 4; ++ni) gacc[mi][ni] = (f4v){0.f, 0.f, 0.f, 0.f};
        #pragma unroll
        for (int ni = 0; ni < 4; ++ni)
            #pragma unroll
            for (int kt = 0; kt < 2; ++kt) {
                s8v bh = *(const s8v*)(wgb + wb + (size_t)(ni * 16 + m16) * 64 + kt * 32 + quad * 8);
                #pragma unroll
                for (int mi = 0; mi < 2; ++mi)
                    gacc[mi][ni] = __builtin_amdgcn_mfma_f32_16x16x32_bf16(c[mi][kt], bh, gacc[mi][ni], 0, 0, 0);
            }

        {
            float xtok[2][4];
            #pragma unroll
            for (int mi = 0; mi < 2; ++mi)
                #pragma unroll
                for (int r = 0; r < 4; ++r) xtok[mi][r] = xs[wave][mi * 16 + quad * 4 + r];
            #pragma unroll
            for (int mi = 0; mi < 2; ++mi)
                #pragma unroll
                for (int ni = 0; ni < 4; ++ni)
                    #pragma unroll
                    for (int r = 0; r < 4; ++r) {
                        float g = sigm_f(gacc[mi][ni][r] + bgd[ni]);
                        gacc[mi][ni][r] = fmaf(xtok[mi][r], wskd[ni], bskd[ni]) + g * hacc[mi][ni][r];
                    }
        }

        #pragma unroll
        for (int mi = 0; mi < 2; ++mi)
            #pragma unroll
            for (int r = 0; r < 4; ++r) {
                float s0 = gacc[mi][0][r], s1 = gacc[mi][1][r], s2 = gacc[mi][2][r], s3 = gacc[mi][3][r];
                float sum = s0 + s1 + s2 + s3;
                float sq  = s0 * s0 + s1 * s1 + s2 * s2 + s3 * s3;
                #pragma unroll
                for (int m = 1; m < 16; m <<= 1) { sum += __shfl_xor(sum, m); sq += __shfl_xor(sq, m); }
                float mu  = sum * 0.015625f;
                float var = sq * 0.015625f - mu * mu;
                float rs  = __builtin_amdgcn_rsqf(var + LN_EPS);
                size_t base = (size_t)(tile0 + mi * 16 + quad * 4 + r) * SROW + (size_t)v * 64 + m16;
                #pragma unroll
                for (int ni = 0; ni < 4; ++ni)
                    stb[base + ni * 16] =
                        bf16_rn((gacc[mi][ni][r] - mu) * rs * gamd[ni] + betd[ni]);
            }
    }
}

// ---------------- Stage 2a: M=64 x N=128 tile, KSPLIT=4, BK=64, 16-deep K loop.
// 256 thr / 4 waves; wave nw covers 32 cols, full 64 rows (acc 4x2).
// global_load_lds staging: linear LDS dest + inverse-XOR-swizzled source +
// XOR-swizzled ds_read (verified pattern from round 1). LDS 48KB -> 3 blocks/CU.
__global__ __launch_bounds__(256) void vsn_stage2a(
    const unsigned short* __restrict__ stb,   // [8192][SROW]
    const short* __restrict__ wct,            // [128][WROW]
    float* __restrict__ part)                 // [8192][PROW2]
{
    const int t = threadIdx.x;
    const int wave = t >> 6, lane = t & 63;
    const int m16 = lane & 15, quad = lane >> 4;
    const int nw = wave;
    const int tok0 = blockIdx.x * MT2;
    const int s = blockIdx.y;
    const int k0 = s * KR2;

    __shared__ __align__(16) unsigned short Al[2][64 * 64];    // 8KB x2
    __shared__ __align__(16) unsigned short Bl[2][128 * 64];   // 16KB x2

    f4v acc[4][2];
    #pragma unroll
    for (int mi = 0; mi < 4; ++mi)
        #pragma unroll
        for (int nj = 0; nj < 2; ++nj) acc[mi][nj] = (f4v){0.f, 0.f, 0.f, 0.f};

    auto STAGE = [&](int buf, int kc) {
        const int kb = k0 + kc * BK;
        // A: 64 rows x 128B; wave covers 16 rows per call, 2 calls
        #pragma unroll
        for (int q = 0; q < 2; ++q) {
            const int row = wave * 16 + q * 8 + (lane >> 3);
            const int sc = ((lane & 7) ^ (row & 7)) * 8;
            async16(stb + (size_t)(tok0 + row) * SROW + kb + sc,
                    &Al[buf][wave * 1024 + q * 512]);
        }
        // B: 128 rows x 128B; wave covers 32 rows (8 per call, 4 calls)
        #pragma unroll
        for (int q = 0; q < 4; ++q) {
            const int row = wave * 32 + q * 8 + (lane >> 3);
            const int sc = ((lane & 7) ^ (row & 7)) * 8;
            async16(wct + (size_t)row * WROW + kb + sc,
                    &Bl[buf][wave * 2048 + q * 512]);
        }
    };

    STAGE(0, 0);
    __syncthreads();                    // drains vmcnt(0): buf0 ready

    for (int kc = 0; kc < NKC; ++kc) {
        const int buf = kc & 1;
        if (kc + 1 < NKC) STAGE(buf ^ 1, kc + 1);
        #pragma unroll
        for (int ks = 0; ks < 2; ++ks) {
            s8v af[4], bfr[2];
            #pragma unroll
            for (int mi = 0; mi < 4; ++mi) {
                int row = mi * 16 + m16;
                int ch = ((ks * 4 + quad) ^ (row & 7)) * 8;
                af[mi] = *(const s8v*)&Al[buf][row * 64 + ch];
            }
            #pragma unroll
            for (int nj = 0; nj < 2; ++nj) {
                int row = nw * 32 + nj * 16 + m16;
                int ch = ((ks * 4 + quad) ^ (row & 7)) * 8;
                bfr[nj] = *(const s8v*)&Bl[buf][row * 64 + ch];
            }
            #pragma unroll
            for (int mi = 0; mi < 4; ++mi)
                #pragma unroll
                for (int nj = 0; nj < 2; ++nj)
                    acc[mi][nj] = __builtin_amdgcn_mfma_f32_16x16x32_bf16(af[mi], bfr[nj], acc[mi][nj], 0, 0, 0);
        }
        __syncthreads();
    }

    #pragma unroll
    for (int mi = 0; mi < 4; ++mi)
        #pragma unroll
        for (int nj = 0; nj < 2; ++nj)
            #pragma unroll
            for (int r = 0; r < 4; ++r)
                part[(size_t)(tok0 + mi * 16 + quad * 4 + r) * PROW2
                     + s * 128 + nw * 32 + nj * 16 + m16] = acc[mi][nj][r];
}

// ---------------- Stage 2b: reduce 4 contiguous partials, tail GRN, softmax, weighted sum
__global__ __launch_bounds__(256) void vsn_stage2b(
    const unsigned short* __restrict__ stb, const float* __restrict__ part,
    const float* __restrict__ bn1,
    const float* __restrict__ Wn2, const float* __restrict__ bn2,
    const float* __restrict__ Wng, const float* __restrict__ bng,
    const float* __restrict__ bns,
    const float* __restrict__ ngamma, const float* __restrict__ nbeta,
    float* __restrict__ out)
{
    const int t = threadIdx.x;
    const int tok0 = blockIdx.x * 8;
    const int lane = t & 63, wv = t >> 6;

    __shared__ __align__(16) float hw1_s[8][64];
    __shared__ __align__(16) float skw_s[8][64];
    __shared__ __align__(16) float hw2_s[8][64];
    __shared__ float s2_s[8][64];
    __shared__ float w_s[8][64];

    // ---- reduce part[tok][0:4][0:128]; contiguous f4 wave-loads
    #pragma unroll
    for (int tk = 0; tk < 2; ++tk) {
        int tl = wv * 2 + tk;
        const float* pr = part + (size_t)(tok0 + tl) * PROW2
                        + (lane >> 5) * 128 + (lane & 31) * 4;
        float tv[4] = {0.f, 0.f, 0.f, 0.f};
        #pragma unroll
        for (int i = 0; i < 2; ++i) {
            float4 a = *(const float4*)(pr + i * 256);
            tv[0] += a.x; tv[1] += a.y; tv[2] += a.z; tv[3] += a.w;
        }
        #pragma unroll
        for (int c = 0; c < 4; ++c) tv[c] += __shfl_xor(tv[c], 32);
        if (lane < 16) {
            int j0 = lane * 4;
            float4 bb = *(const float4*)(bn1 + j0);
            hw1_s[tl][j0 + 0] = elu_f(tv[0] + bb.x);
            hw1_s[tl][j0 + 1] = elu_f(tv[1] + bb.y);
            hw1_s[tl][j0 + 2] = elu_f(tv[2] + bb.z);
            hw1_s[tl][j0 + 3] = elu_f(tv[3] + bb.w);
        } else if (lane < 32) {
            int j0 = (lane - 16) * 4;
            float4 bb = *(const float4*)(bns + j0);
            skw_s[tl][j0 + 0] = tv[0] + bb.x;
            skw_s[tl][j0 + 1] = tv[1] + bb.y;
            skw_s[tl][j0 + 2] = tv[2] + bb.z;
            skw_s[tl][j0 + 3] = tv[3] + bb.w;
        }
    }
    __syncthreads();

    // ---- hw2 = hw1 @ Wn2 + bn2
    #pragma unroll
    for (int i = 0; i < 2; ++i) {
        int oidx = i * 256 + t;
        int tt = oidx >> 6, jj = oidx & 63;
        float acc = bn2[jj];
        #pragma unroll
        for (int k4 = 0; k4 < 16; ++k4) {
            float4 h = *(const float4*)&hw1_s[tt][k4 * 4];
            acc += h.x * Wn2[(k4*4+0)*64+jj] + h.y * Wn2[(k4*4+1)*64+jj]
                 + h.z * Wn2[(k4*4+2)*64+jj] + h.w * Wn2[(k4*4+3)*64+jj];
        }
        hw2_s[tt][jj] = acc;
    }
    __syncthreads();

    // ---- gw = sigmoid(hw2 @ Wng + bng); s2 = skw + gw*hw2
    #pragma unroll
    for (int i = 0; i < 2; ++i) {
        int oidx = i * 256 + t;
        int tt = oidx >> 6, vv = oidx & 63;
        float acc = bng[vv];
        #pragma unroll
        for (int k4 = 0; k4 < 16; ++k4) {
            float4 h = *(const float4*)&hw2_s[tt][k4 * 4];
            acc += h.x * Wng[(k4*4+0)*64+vv] + h.y * Wng[(k4*4+1)*64+vv]
                 + h.z * Wng[(k4*4+2)*64+vv] + h.w * Wng[(k4*4+3)*64+vv];
        }
        float gw = sigm_f(acc);
        s2_s[tt][vv] = skw_s[tt][vv] + gw * hw2_s[tt][vv];
    }
    __syncthreads();

    // ---- HOISTED stb loads for the weighted sum
    const int vloc = lane >> 3, d8 = (lane & 7) * 8;
    s8v r0[8], r1[8];
    {
        const short* s0 = (const short*)stb + (size_t)(tok0 + wv * 2) * SROW + d8;
        const short* s1 = s0 + SROW;
        #pragma unroll
        for (int vc = 0; vc < 8; ++vc) {
            r0[vc] = *(const s8v*)(s0 + (vc * 8 + vloc) * 64);
            r1[vc] = *(const s8v*)(s1 + (vc * 8 + vloc) * 64);
        }
    }

    // ---- LN over v + softmax; 16 lanes per token
    if (t < 128) {
        int tt = t >> 4, l = t & 15;
        float z[4]; float sum = 0.f, sq = 0.f;
        #pragma unroll
        for (int i = 0; i < 4; ++i) { z[i] = s2_s[tt][l + 16 * i]; sum += z[i]; sq += z[i] * z[i]; }
        #pragma unroll
        for (int m = 1; m < 16; m <<= 1) { sum += __shfl_xor(sum, m); sq += __shfl_xor(sq, m); }
        float mu  = sum * 0.015625f;
        float var = sq * 0.015625f - mu * mu;
        float rs  = __builtin_amdgcn_rsqf(var + LN_EPS);
        float ln[4]; float mx = -1e30f;
        #pragma unroll
        for (int i = 0; i < 4; ++i) {
            ln[i] = (z[i] - mu) * rs * ngamma[l + 16 * i] + nbeta[l + 16 * i];
            mx = fmaxf(mx, ln[i]);
        }
        #pragma unroll
        for (int m = 1; m < 16; m <<= 1) mx = fmaxf(mx, __shfl_xor(mx, m));
        float es = 0.f; float ev[4];
        #pragma unroll
        for (int i = 0; i < 4; ++i) { ev[i] = __expf(ln[i] - mx); es += ev[i]; }
        #pragma unroll
        for (int m = 1; m < 16; m <<= 1) es += __shfl_xor(es, m);
        float inv = __builtin_amdgcn_rcpf(es);
        #pragma unroll
        for (int i = 0; i < 4; ++i) w_s[tt][l + 16 * i] = ev[i] * inv;
    }
    __syncthreads();

    // ---- weighted sum from the hoisted registers
    {
        float acc0[8], acc1[8];
        #pragma unroll
        for (int j = 0; j < 8; ++j) { acc0[j] = 0.f; acc1[j] = 0.f; }
        #pragma unroll
        for (int vc = 0; vc < 8; ++vc) {
            int v = vc * 8 + vloc;
            float w0 = w_s[wv * 2][v], w1 = w_s[wv * 2 + 1][v];
            #pragma unroll
            for (int j = 0; j < 8; ++j) {
                acc0[j] = fmaf(w0, bf16_to_f((unsigned short)r0[vc][j]), acc0[j]);
                acc1[j] = fmaf(w1, bf16_to_f((unsigned short)r1[vc][j]), acc1[j]);
            }
        }
        #pragma unroll
        for (int m = 8; m <= 32; m <<= 1)
            #pragma unroll
            for (int j = 0; j < 8; ++j) {
                acc0[j] += __shfl_xor(acc0[j], m);
                acc1[j] += __shfl_xor(acc1[j], m);
            }
        if (lane < 8) {
            float* op = out + (size_t)(tok0 + wv * 2) * 64 + lane * 8;
            *(float4*)op       = make_float4(acc0[0], acc0[1], acc0[2], acc0[3]);
            *(float4*)(op + 4) = make_float4(acc0[4], acc0[5], acc0[6], acc0[7]);
            op += 64;
            *(float4*)op       = make_float4(acc1[0], acc1[1], acc1[2], acc1[3]);
            *(float4*)(op + 4) = make_float4(acc1[4], acc1[5], acc1[6], acc1[7]);
        }
    }
}

extern "C" void kernel_launch(void* const* d_in, const int* in_sizes, int n_in,
                              void* d_out, int out_size, void* d_ws, size_t ws_size,
                              hipStream_t stream) {
    const float* x     = (const float*)d_in[0];
    const float* W1    = (const float*)d_in[1];
    const float* b1    = (const float*)d_in[2];
    const float* W2    = (const float*)d_in[3];
    const float* b2    = (const float*)d_in[4];
    const float* Wg    = (const float*)d_in[5];
    const float* bg    = (const float*)d_in[6];
    const float* Wsk   = (const float*)d_in[7];
    const float* bsk   = (const float*)d_in[8];
    const float* gamma = (const float*)d_in[9];
    const float* beta  = (const float*)d_in[10];
    const float* Wn1   = (const float*)d_in[11];
    const float* bn1   = (const float*)d_in[12];
    const float* Wn2   = (const float*)d_in[13];
    const float* bn2   = (const float*)d_in[14];
    const float* Wng   = (const float*)d_in[15];
    const float* bng   = (const float*)d_in[16];
    const float* Wns   = (const float*)d_in[17];
    const float* bns   = (const float*)d_in[18];
    const float* ngam  = (const float*)d_in[19];
    const float* nbet  = (const float*)d_in[20];

    char* ws = (char*)d_ws;
    unsigned short* stb = (unsigned short*)ws;                   // 64 MiB
    short* wct = (short*)(ws + (64u << 20));                     // 1 MiB
    short* w2b = (short*)(ws + (65u << 20));                     // 512 KiB each
    short* wgb = w2b + 262144;
    float* part = (float*)(ws + (66u << 20));                    // 16 MiB (8192 x 512)
    float* outp = (float*)d_out;

    vsn_prepack<<<dim3(192), 256, 0, stream>>>(W2, Wg, Wn1, Wns, w2b, wgb, wct);
    vsn_stage1<<<dim3(NTOK / 128, 16), 256, 0, stream>>>(
        x, W1, b1, w2b, wgb, b2, bg, Wsk, bsk, gamma, beta, stb);
    vsn_stage2a<<<dim3(NTOK / MT2, KSPLIT), 256, 0, stream>>>(stb, wct, part);
    vsn_stage2b<<<dim3(NTOK / 8), 256, 0, stream>>>(
        stb, part, bn1, Wn2, bn2, Wng, bng, bns, ngam, nbet, outp);
}

// Round 3
// 185.190 us; speedup vs baseline: 1.0593x; 1.0284x over previous
//
#include <hip/hip_runtime.h>
#include <hip/hip_bf16.h>
#include <math.h>

#define NV 64
#define ND 64
#define NTOK 8192
#define LN_EPS 1e-5f
#define SROW 4096
#define WROW 4096
#define KSPLIT 8
#define KR2 (4096 / KSPLIT)     // 512
#define BK 64
#define NKC (KR2 / BK)          // 8
#define PROW2 (KSPLIT * 128)    // 1024

typedef __attribute__((ext_vector_type(8))) short s8v;    // 8 bf16 = 4 VGPR
typedef __attribute__((ext_vector_type(4))) float f4v;    // MFMA C/D
typedef __attribute__((ext_vector_type(4))) int   i4v;

__device__ __forceinline__ float sigm_f(float x) {
    return __builtin_amdgcn_rcpf(1.f + __expf(-x));
}
__device__ __forceinline__ float elu_f(float x)  { return x > 0.f ? x : (__expf(x) - 1.f); }

__device__ __forceinline__ float bf16_to_f(unsigned short s) {
    union { unsigned int u; float f; } c; c.u = ((unsigned int)s) << 16;
    return c.f;
}
__device__ __forceinline__ unsigned short bf16_rn(float f) {
    union { float f; unsigned int u; } c; c.f = f;
    return (unsigned short)((c.u + 0x8000u) >> 16);
}
// async global->LDS 16B (lds base wave-uniform; lane l writes base + l*16B)
__device__ __forceinline__ void async16(const void* g, void* l) {
    __builtin_amdgcn_global_load_lds(
        (const __attribute__((address_space(1))) unsigned int*)g,
        (__attribute__((address_space(3))) unsigned int*)l,
        16, 0, 0);
}

// ---------------- Prepack: weight transposes via LDS tiles (coalesced R+W)
__global__ __launch_bounds__(256) void vsn_prepack(
    const float* __restrict__ W2, const float* __restrict__ Wg,
    const float* __restrict__ Wn1, const float* __restrict__ Wns,
    short* __restrict__ w2b, short* __restrict__ wgb,
    short* __restrict__ wct)
{
    __shared__ float T[64][65];
    const int b = blockIdx.x, t = threadIdx.x;

    if (b < 64) {
        const float* src = W2 + (size_t)b * 4096;
        short* dst = w2b + (size_t)b * 4096;
        #pragma unroll
        for (int pass = 0; pass < 2; ++pass) {
            #pragma unroll
            for (int i = 0; i < 16; ++i) {
                int id = i * 256 + t;
                T[id & 63][id >> 6] = src[id];
            }
            __syncthreads();
            #pragma unroll
            for (int i = 0; i < 16; ++i) {
                int id = i * 256 + t;
                dst[id] = (short)bf16_rn(T[id >> 6][id & 63]);
            }
            __syncthreads();
            src = Wg + (size_t)b * 4096;
            dst = wgb + (size_t)b * 4096;
        }
    } else {
        int tb = b - 64;
        int half = tb >> 6, kt = tb & 63;
        const float* src = (half == 0 ? Wn1 : Wns) + (size_t)(kt * 64) * 64;
        #pragma unroll
        for (int i = 0; i < 16; ++i) {
            int id = i * 256 + t;
            T[id & 63][id >> 6] = src[id];
        }
        __syncthreads();
        #pragma unroll
        for (int i = 0; i < 16; ++i) {
            int id = i * 256 + t;
            int n = id >> 6, r = id & 63;
            wct[(size_t)(half * 64 + n) * WROW + kt * 64 + r] = (short)bf16_rn(T[n][r]);
        }
    }
}

// ---------------- Stage 1: verified round-0 version (~50us).
__global__ __launch_bounds__(256) void vsn_stage1(
    const float* __restrict__ x,
    const float* __restrict__ W1, const float* __restrict__ b1,
    const short* __restrict__ w2b, const short* __restrict__ wgb,
    const float* __restrict__ b2, const float* __restrict__ bg,
    const float* __restrict__ Wsk, const float* __restrict__ bsk,
    const float* __restrict__ gamma, const float* __restrict__ beta,
    unsigned short* __restrict__ stb)
{
    const int t = threadIdx.x;
    const int wave = t >> 6, lane = t & 63;
    const int m16 = lane & 15, quad = lane >> 4;
    const int v = blockIdx.y * 4 + wave;

    __shared__ float xs[4][32];
    __shared__ __align__(16) unsigned short h2s[4][32][72];

    float w1k[2][8], b1k[2][8];
    #pragma unroll
    for (int kt = 0; kt < 2; ++kt) {
        *(float4*)&w1k[kt][0] = *(const float4*)(W1 + v * 64 + kt * 32 + quad * 8);
        *(float4*)&w1k[kt][4] = *(const float4*)(W1 + v * 64 + kt * 32 + quad * 8 + 4);
        *(float4*)&b1k[kt][0] = *(const float4*)(b1 + v * 64 + kt * 32 + quad * 8);
        *(float4*)&b1k[kt][4] = *(const float4*)(b1 + v * 64 + kt * 32 + quad * 8 + 4);
    }
    float b2d[4], bgd[4], wskd[4], bskd[4], gamd[4], betd[4];
    #pragma unroll
    for (int ni = 0; ni < 4; ++ni) {
        int d = v * 64 + ni * 16 + m16;
        b2d[ni] = b2[d]; bgd[ni] = bg[d]; wskd[ni] = Wsk[d]; bskd[ni] = bsk[d];
        gamd[ni] = gamma[d]; betd[ni] = beta[d];
    }
    const size_t wb = (size_t)v * 4096;

    for (int tt4 = 0; tt4 < 4; ++tt4) {
        const int tile0 = blockIdx.x * 128 + tt4 * 32;

        if (lane < 32) xs[wave][lane] = x[(size_t)(tile0 + lane) * NV + v];

        s8v a[2][2];
        #pragma unroll
        for (int kt = 0; kt < 2; ++kt)
            #pragma unroll
            for (int mi = 0; mi < 2; ++mi) {
                float xv = xs[wave][mi * 16 + m16];
                float h[8];
                #pragma unroll
                for (int j = 0; j < 8; ++j) h[j] = elu_f(fmaf(xv, w1k[kt][j], b1k[kt][j]));
                i4v av;
                #pragma unroll
                for (int p = 0; p < 4; ++p) {
                    unsigned int u0 = __float_as_uint(h[2 * p]);
                    unsigned int u1 = __float_as_uint(h[2 * p + 1]);
                    av[p] = (int)((u1 & 0xffff0000u) | (u0 >> 16));
                }
                a[mi][kt] = *(s8v*)&av;
            }

        f4v hacc[2][4];
        #pragma unroll
        for (int mi = 0; mi < 2; ++mi)
            #pragma unroll
            for (int ni = 0; ni < 4; ++ni) hacc[mi][ni] = (f4v){0.f, 0.f, 0.f, 0.f};
        #pragma unroll
        for (int ni = 0; ni < 4; ++ni)
            #pragma unroll
            for (int kt = 0; kt < 2; ++kt) {
                s8v bh = *(const s8v*)(w2b + wb + (size_t)(ni * 16 + m16) * 64 + kt * 32 + quad * 8);
                #pragma unroll
                for (int mi = 0; mi < 2; ++mi)
                    hacc[mi][ni] = __builtin_amdgcn_mfma_f32_16x16x32_bf16(a[mi][kt], bh, hacc[mi][ni], 0, 0, 0);
            }
        #pragma unroll
        for (int mi = 0; mi < 2; ++mi)
            #pragma unroll
            for (int ni = 0; ni < 4; ++ni)
                #pragma unroll
                for (int r = 0; r < 4; ++r) hacc[mi][ni][r] += b2d[ni];

        #pragma unroll
        for (int mi = 0; mi < 2; ++mi)
            #pragma unroll
            for (int ni = 0; ni < 4; ++ni)
                #pragma unroll
                for (int r = 0; r < 4; ++r)
                    h2s[wave][mi * 16 + quad * 4 + r][ni * 16 + m16] =
                        (unsigned short)(__float_as_uint(hacc[mi][ni][r]) >> 16);

        s8v c[2][2];
        #pragma unroll
        for (int mi = 0; mi < 2; ++mi)
            #pragma unroll
            for (int kt = 0; kt < 2; ++kt)
                c[mi][kt] = *(const s8v*)&h2s[wave][mi * 16 + m16][kt * 32 + quad * 8];

        f4v gacc[2][4];
        #pragma unroll
        for (int mi = 0; mi < 2; ++mi)
            #pragma unroll
            for (int ni = 0; ni < 4; ++ni) gacc[mi][ni] = (f4v){0.f, 0.f, 0.f, 0.f};
        #pragma unroll
        for (int ni = 0; ni < 4; ++ni)
            #pragma unroll
            for (int kt = 0; kt < 2; ++kt) {
                s8v bh = *(const s8v*)(wgb + wb + (size_t)(ni * 16 + m16) * 64 + kt * 32 + quad * 8);
                #pragma unroll
                for (int mi = 0; mi < 2; ++mi)
                    gacc[mi][ni] = __builtin_amdgcn_mfma_f32_16x16x32_bf16(c[mi][kt], bh, gacc[mi][ni], 0, 0, 0);
            }

        {
            float xtok[2][4];
            #pragma unroll
            for (int mi = 0; mi < 2; ++mi)
                #pragma unroll
                for (int r = 0; r < 4; ++r) xtok[mi][r] = xs[wave][mi * 16 + quad * 4 + r];
            #pragma unroll
            for (int mi = 0; mi < 2; ++mi)
                #pragma unroll
                for (int ni = 0; ni < 4; ++ni)
                    #pragma unroll
                    for (int r = 0; r < 4; ++r) {
                        float g = sigm_f(gacc[mi][ni][r] + bgd[ni]);
                        gacc[mi][ni][r] = fmaf(xtok[mi][r], wskd[ni], bskd[ni]) + g * hacc[mi][ni][r];
                    }
        }

        #pragma unroll
        for (int mi = 0; mi < 2; ++mi)
            #pragma unroll
            for (int r = 0; r < 4; ++r) {
                float s0 = gacc[mi][0][r], s1 = gacc[mi][1][r], s2 = gacc[mi][2][r], s3 = gacc[mi][3][r];
                float sum = s0 + s1 + s2 + s3;
                float sq  = s0 * s0 + s1 * s1 + s2 * s2 + s3 * s3;
                #pragma unroll
                for (int m = 1; m < 16; m <<= 1) { sum += __shfl_xor(sum, m); sq += __shfl_xor(sq, m); }
                float mu  = sum * 0.015625f;
                float var = sq * 0.015625f - mu * mu;
                float rs  = __builtin_amdgcn_rsqf(var + LN_EPS);
                size_t base = (size_t)(tile0 + mi * 16 + quad * 4 + r) * SROW + (size_t)v * 64 + m16;
                #pragma unroll
                for (int ni = 0; ni < 4; ++ni)
                    stb[base + ni * 16] =
                        bf16_rn((gacc[mi][ni][r] - mu) * rs * gamd[ni] + betd[ni]);
            }
    }
}

// ---------------- Stage 2a: M=128 x N=128, KSPLIT=8, BK=64, 512 thr / 8 waves.
// Distance-2 prefetch + counted vmcnt (T4-lite): loop-top waits vmcnt(4) (stage
// from 2 steps ago), raw s_barrier (NO vmcnt(0) drain), compute, barrier, issue
// STAGE(kc+2). Staging: linear LDS dest + inverse-XOR-swizzled source +
// XOR-swizzled ds_read (verified r1/r2).
__global__ __launch_bounds__(512) void vsn_stage2a(
    const unsigned short* __restrict__ stb,   // [8192][SROW]
    const short* __restrict__ wct,            // [128][WROW]
    float* __restrict__ part)                 // [8192][PROW2]
{
    const int t = threadIdx.x;
    const int wave = t >> 6, lane = t & 63;
    const int m16 = lane & 15, quad = lane >> 4;
    const int mw = wave & 3, nw = wave >> 2;
    const int tok0 = blockIdx.x * 128;
    const int s = blockIdx.y;
    const int k0 = s * KR2;

    __shared__ __align__(16) unsigned short Al[2][128 * 64];   // 16KB x2
    __shared__ __align__(16) unsigned short Bl[2][128 * 64];   // 16KB x2

    const int srow = t >> 3;            // 0..63 (+64 for q=1)
    const int schunk = t & 7;           // 16B chunk within the 128B row

    f4v acc[2][4];
    #pragma unroll
    for (int mi = 0; mi < 2; ++mi)
        #pragma unroll
        for (int nj = 0; nj < 4; ++nj) acc[mi][nj] = (f4v){0.f, 0.f, 0.f, 0.f};

    auto STAGE = [&](int buf, int kc) {
        const int kb = k0 + kc * BK;
        #pragma unroll
        for (int q = 0; q < 2; ++q) {
            const int row = srow + q * 64;
            const int sc = (schunk ^ (row & 7)) * 8;   // inverse-swizzled source col
            async16(stb + (size_t)(tok0 + row) * SROW + kb + sc,
                    &Al[buf][q * 4096 + wave * 512]);
            async16(wct + (size_t)row * WROW + kb + sc,
                    &Bl[buf][q * 4096 + wave * 512]);
        }
    };

    // prologue: 2 stages in flight (4 loads/lane each)
    STAGE(0, 0);
    STAGE(1, 1);

    for (int kc = 0; kc < NKC; ++kc) {
        const int buf = kc & 1;
        // wait for stage kc only (stage kc+1's 4 loads stay in flight)
        if (kc + 1 < NKC) asm volatile("s_waitcnt vmcnt(4)" ::: "memory");
        else              asm volatile("s_waitcnt vmcnt(0)" ::: "memory");
        __builtin_amdgcn_s_barrier();
        __builtin_amdgcn_sched_barrier(0);

        #pragma unroll
        for (int ks = 0; ks < 2; ++ks) {
            s8v af[2], bfr[4];
            #pragma unroll
            for (int mi = 0; mi < 2; ++mi) {
                int row = mw * 32 + mi * 16 + m16;
                int ch = ((ks * 4 + quad) ^ (row & 7)) * 8;     // swizzled read
                af[mi] = *(const s8v*)&Al[buf][row * 64 + ch];
            }
            #pragma unroll
            for (int nj = 0; nj < 4; ++nj) {
                int row = nw * 64 + nj * 16 + m16;
                int ch = ((ks * 4 + quad) ^ (row & 7)) * 8;
                bfr[nj] = *(const s8v*)&Bl[buf][row * 64 + ch];
            }
            #pragma unroll
            for (int mi = 0; mi < 2; ++mi)
                #pragma unroll
                for (int nj = 0; nj < 4; ++nj)
                    acc[mi][nj] = __builtin_amdgcn_mfma_f32_16x16x32_bf16(af[mi], bfr[nj], acc[mi][nj], 0, 0, 0);
        }

        // all waves done reading buf before it is overwritten by stage kc+2
        asm volatile("s_waitcnt lgkmcnt(0)" ::: "memory");
        __builtin_amdgcn_s_barrier();
        __builtin_amdgcn_sched_barrier(0);
        if (kc + 2 < NKC) STAGE(buf, kc + 2);
    }

    #pragma unroll
    for (int mi = 0; mi < 2; ++mi)
        #pragma unroll
        for (int nj = 0; nj < 4; ++nj)
            #pragma unroll
            for (int r = 0; r < 4; ++r)
                part[(size_t)(tok0 + mw * 32 + mi * 16 + quad * 4 + r) * PROW2
                     + s * 128 + nw * 64 + nj * 16 + m16] = acc[mi][nj][r];
}

// ---------------- Stage 2b: reduce 8 contiguous partials, tail GRN, softmax, weighted sum
__global__ __launch_bounds__(256) void vsn_stage2b(
    const unsigned short* __restrict__ stb, const float* __restrict__ part,
    const float* __restrict__ bn1,
    const float* __restrict__ Wn2, const float* __restrict__ bn2,
    const float* __restrict__ Wng, const float* __restrict__ bng,
    const float* __restrict__ bns,
    const float* __restrict__ ngamma, const float* __restrict__ nbeta,
    float* __restrict__ out)
{
    const int t = threadIdx.x;
    const int tok0 = blockIdx.x * 8;
    const int lane = t & 63, wv = t >> 6;

    __shared__ __align__(16) float hw1_s[8][64];
    __shared__ __align__(16) float skw_s[8][64];
    __shared__ __align__(16) float hw2_s[8][64];
    __shared__ float s2_s[8][64];
    __shared__ float w_s[8][64];

    // ---- reduce part[tok][0:8][0:128]; contiguous f4 wave-loads
    #pragma unroll
    for (int tk = 0; tk < 2; ++tk) {
        int tl = wv * 2 + tk;
        const float* pr = part + (size_t)(tok0 + tl) * PROW2
                        + (lane >> 5) * 128 + (lane & 31) * 4;
        float tv[4] = {0.f, 0.f, 0.f, 0.f};
        #pragma unroll
        for (int i = 0; i < 4; ++i) {
            float4 a = *(const float4*)(pr + i * 256);
            tv[0] += a.x; tv[1] += a.y; tv[2] += a.z; tv[3] += a.w;
        }
        #pragma unroll
        for (int c = 0; c < 4; ++c) tv[c] += __shfl_xor(tv[c], 32);
        if (lane < 16) {
            int j0 = lane * 4;
            float4 bb = *(const float4*)(bn1 + j0);
            hw1_s[tl][j0 + 0] = elu_f(tv[0] + bb.x);
            hw1_s[tl][j0 + 1] = elu_f(tv[1] + bb.y);
            hw1_s[tl][j0 + 2] = elu_f(tv[2] + bb.z);
            hw1_s[tl][j0 + 3] = elu_f(tv[3] + bb.w);
        } else if (lane < 32) {
            int j0 = (lane - 16) * 4;
            float4 bb = *(const float4*)(bns + j0);
            skw_s[tl][j0 + 0] = tv[0] + bb.x;
            skw_s[tl][j0 + 1] = tv[1] + bb.y;
            skw_s[tl][j0 + 2] = tv[2] + bb.z;
            skw_s[tl][j0 + 3] = tv[3] + bb.w;
        }
    }
    __syncthreads();

    // ---- hw2 = hw1 @ Wn2 + bn2
    #pragma unroll
    for (int i = 0; i < 2; ++i) {
        int oidx = i * 256 + t;
        int tt = oidx >> 6, jj = oidx & 63;
        float acc = bn2[jj];
        #pragma unroll
        for (int k4 = 0; k4 < 16; ++k4) {
            float4 h = *(const float4*)&hw1_s[tt][k4 * 4];
            acc += h.x * Wn2[(k4*4+0)*64+jj] + h.y * Wn2[(k4*4+1)*64+jj]
                 + h.z * Wn2[(k4*4+2)*64+jj] + h.w * Wn2[(k4*4+3)*64+jj];
        }
        hw2_s[tt][jj] = acc;
    }
    __syncthreads();

    // ---- gw = sigmoid(hw2 @ Wng + bng); s2 = skw + gw*hw2
    #pragma unroll
    for (int i = 0; i < 2; ++i) {
        int oidx = i * 256 + t;
        int tt = oidx >> 6, vv = oidx & 63;
        float acc = bng[vv];
        #pragma unroll
        for (int k4 = 0; k4 < 16; ++k4) {
            float4 h = *(const float4*)&hw2_s[tt][k4 * 4];
            acc += h.x * Wng[(k4*4+0)*64+vv] + h.y * Wng[(k4*4+1)*64+vv]
                 + h.z * Wng[(k4*4+2)*64+vv] + h.w * Wng[(k4*4+3)*64+vv];
        }
        float gw = sigm_f(acc);
        s2_s[tt][vv] = skw_s[tt][vv] + gw * hw2_s[tt][vv];
    }
    __syncthreads();

    // ---- HOISTED stb loads for the weighted sum
    const int vloc = lane >> 3, d8 = (lane & 7) * 8;
    s8v r0[8], r1[8];
    {
        const short* s0 = (const short*)stb + (size_t)(tok0 + wv * 2) * SROW + d8;
        const short* s1 = s0 + SROW;
        #pragma unroll
        for (int vc = 0; vc < 8; ++vc) {
            r0[vc] = *(const s8v*)(s0 + (vc * 8 + vloc) * 64);
            r1[vc] = *(const s8v*)(s1 + (vc * 8 + vloc) * 64);
        }
    }

    // ---- LN over v + softmax; 16 lanes per token
    if (t < 128) {
        int tt = t >> 4, l = t & 15;
        float z[4]; float sum = 0.f, sq = 0.f;
        #pragma unroll
        for (int i = 0; i < 4; ++i) { z[i] = s2_s[tt][l + 16 * i]; sum += z[i]; sq += z[i] * z[i]; }
        #pragma unroll
        for (int m = 1; m < 16; m <<= 1) { sum += __shfl_xor(sum, m); sq += __shfl_xor(sq, m); }
        float mu  = sum * 0.015625f;
        float var = sq * 0.015625f - mu * mu;
        float rs  = __builtin_amdgcn_rsqf(var + LN_EPS);
        float ln[4]; float mx = -1e30f;
        #pragma unroll
        for (int i = 0; i < 4; ++i) {
            ln[i] = (z[i] - mu) * rs * ngamma[l + 16 * i] + nbeta[l + 16 * i];
            mx = fmaxf(mx, ln[i]);
        }
        #pragma unroll
        for (int m = 1; m < 16; m <<= 1) mx = fmaxf(mx, __shfl_xor(mx, m));
        float es = 0.f; float ev[4];
        #pragma unroll
        for (int i = 0; i < 4; ++i) { ev[i] = __expf(ln[i] - mx); es += ev[i]; }
        #pragma unroll
        for (int m = 1; m < 16; m <<= 1) es += __shfl_xor(es, m);
        float inv = __builtin_amdgcn_rcpf(es);
        #pragma unroll
        for (int i = 0; i < 4; ++i) w_s[tt][l + 16 * i] = ev[i] * inv;
    }
    __syncthreads();

    // ---- weighted sum from the hoisted registers
    {
        float acc0[8], acc1[8];
        #pragma unroll
        for (int j = 0; j < 8; ++j) { acc0[j] = 0.f; acc1[j] = 0.f; }
        #pragma unroll
        for (int vc = 0; vc < 8; ++vc) {
            int v = vc * 8 + vloc;
            float w0 = w_s[wv * 2][v], w1 = w_s[wv * 2 + 1][v];
            #pragma unroll
            for (int j = 0; j < 8; ++j) {
                acc0[j] = fmaf(w0, bf16_to_f((unsigned short)r0[vc][j]), acc0[j]);
                acc1[j] = fmaf(w1, bf16_to_f((unsigned short)r1[vc][j]), acc1[j]);
            }
        }
        #pragma unroll
        for (int m = 8; m <= 32; m <<= 1)
            #pragma unroll
            for (int j = 0; j < 8; ++j) {
                acc0[j] += __shfl_xor(acc0[j], m);
                acc1[j] += __shfl_xor(acc1[j], m);
            }
        if (lane < 8) {
            float* op = out + (size_t)(tok0 + wv * 2) * 64 + lane * 8;
            *(float4*)op       = make_float4(acc0[0], acc0[1], acc0[2], acc0[3]);
            *(float4*)(op + 4) = make_float4(acc0[4], acc0[5], acc0[6], acc0[7]);
            op += 64;
            *(float4*)op       = make_float4(acc1[0], acc1[1], acc1[2], acc1[3]);
            *(float4*)(op + 4) = make_float4(acc1[4], acc1[5], acc1[6], acc1[7]);
        }
    }
}

extern "C" void kernel_launch(void* const* d_in, const int* in_sizes, int n_in,
                              void* d_out, int out_size, void* d_ws, size_t ws_size,
                              hipStream_t stream) {
    const float* x     = (const float*)d_in[0];
    const float* W1    = (const float*)d_in[1];
    const float* b1    = (const float*)d_in[2];
    const float* W2    = (const float*)d_in[3];
    const float* b2    = (const float*)d_in[4];
    const float* Wg    = (const float*)d_in[5];
    const float* bg    = (const float*)d_in[6];
    const float* Wsk   = (const float*)d_in[7];
    const float* bsk   = (const float*)d_in[8];
    const float* gamma = (const float*)d_in[9];
    const float* beta  = (const float*)d_in[10];
    const float* Wn1   = (const float*)d_in[11];
    const float* bn1   = (const float*)d_in[12];
    const float* Wn2   = (const float*)d_in[13];
    const float* bn2   = (const float*)d_in[14];
    const float* Wng   = (const float*)d_in[15];
    const float* bng   = (const float*)d_in[16];
    const float* Wns   = (const float*)d_in[17];
    const float* bns   = (const float*)d_in[18];
    const float* ngam  = (const float*)d_in[19];
    const float* nbet  = (const float*)d_in[20];

    char* ws = (char*)d_ws;
    unsigned short* stb = (unsigned short*)ws;                   // 64 MiB
    short* wct = (short*)(ws + (64u << 20));                     // 1 MiB
    short* w2b = (short*)(ws + (65u << 20));                     // 512 KiB each
    short* wgb = w2b + 262144;
    float* part = (float*)(ws + (66u << 20));                    // 32 MiB (8192 x 1024)
    float* outp = (float*)d_out;

    vsn_prepack<<<dim3(192), 256, 0, stream>>>(W2, Wg, Wn1, Wns, w2b, wgb, wct);
    vsn_stage1<<<dim3(NTOK / 128, 16), 256, 0, stream>>>(
        x, W1, b1, w2b, wgb, b2, bg, Wsk, bsk, gamma, beta, stb);
    vsn_stage2a<<<dim3(NTOK / 128, KSPLIT), 512, 0, stream>>>(stb, wct, part);
    vsn_stage2b<<<dim3(NTOK / 8), 256, 0, stream>>>(
        stb, part, bn1, Wn2, bn2, Wng, bng, bns, ngam, nbet, outp);
}